// Round 1
// baseline (414.413 us; speedup 1.0000x reference)
//
#include <hip/hip_runtime.h>

// CoupleLoss: protos = id_prototypes with rows[label] := teachor_ftr (last write wins),
// gi = protos[idH[label,:K]], loss = mean(relu(dot(gi, ftr - teachor_ftr) - MARGIN))
// (since smrs - tmrs = dot(gi, ftr) - dot(gi, teachor) = dot(gi, ftr - teachor)).

#define NUM_IDS 100000
#define FEAT    512
#define BATCH   512
#define KNEG    100
#define MARGIN  0.03f

// Kernel 1: init id->batch map to -1, zero the output accumulator.
__global__ void init_map_kernel(int* __restrict__ map, float* __restrict__ out) {
    int i = blockIdx.x * blockDim.x + threadIdx.x;
    if (i < NUM_IDS) map[i] = -1;
    if (i == 0) *out = 0.0f;
}

// Kernel 2: scatter labels. atomicMax => highest batch index wins, matching
// numpy fancy-assignment last-write-wins semantics for duplicate labels.
__global__ void scatter_map_kernel(const int* __restrict__ label, int* __restrict__ map) {
    int b = threadIdx.x;  // 512 threads, 1 block
    atomicMax(&map[label[b]], b);
}

// Kernel 3: one wave (64 lanes) per (b, k) pair. 51200 pairs / 4 waves per block
// = 12800 blocks -> ~50 blocks/CU queued, good latency hiding for the random
// 2KB row gather (the dominant cost).
__global__ __launch_bounds__(256) void couple_loss_kernel(
    const float* __restrict__ ftr,
    const float* __restrict__ tftr,
    const int*   __restrict__ label,
    const float* __restrict__ protos,
    const int*   __restrict__ idH,
    const int*   __restrict__ map,
    float*       __restrict__ out)
{
    const int wave = threadIdx.x >> 6;
    const int lane = threadIdx.x & 63;
    const int pair = blockIdx.x * 4 + wave;   // 51200 pairs exactly, no bounds check
    const int b = pair / KNEG;                // compiler emits magic-mul divide
    const int k = pair - b * KNEG;

    const int lbl = label[b];
    const int nid = idH[lbl * KNEG + k];
    const int m   = map[nid];
    // Row redirect: if this id was overwritten by the scatter, read teachor row.
    const float* g = (m >= 0) ? (tftr + (size_t)m * FEAT)
                              : (protos + (size_t)nid * FEAT);

    const float4* g4 = (const float4*)g;
    const float4* f4 = (const float4*)(ftr  + (size_t)b * FEAT);
    const float4* t4 = (const float4*)(tftr + (size_t)b * FEAT);

    // 8 elems/lane: [lane*4 .. lane*4+3] and [256 + lane*4 .. +3]
    float4 ga = g4[lane], gb = g4[lane + 64];
    float4 fa = f4[lane], fb = f4[lane + 64];
    float4 ta = t4[lane], tb = t4[lane + 64];

    float p = ga.x * (fa.x - ta.x) + ga.y * (fa.y - ta.y)
            + ga.z * (fa.z - ta.z) + ga.w * (fa.w - ta.w)
            + gb.x * (fb.x - tb.x) + gb.y * (fb.y - tb.y)
            + gb.z * (fb.z - tb.z) + gb.w * (fb.w - tb.w);

    // wave64 butterfly reduction
    #pragma unroll
    for (int off = 32; off >= 1; off >>= 1)
        p += __shfl_xor(p, off, 64);

    __shared__ float wsum[4];
    if (lane == 0) wsum[wave] = fmaxf(p - MARGIN, 0.0f);
    __syncthreads();
    if (threadIdx.x == 0) {
        float s = (wsum[0] + wsum[1] + wsum[2] + wsum[3]) * (1.0f / (BATCH * KNEG));
        atomicAdd(out, s);
    }
}

extern "C" void kernel_launch(void* const* d_in, const int* in_sizes, int n_in,
                              void* d_out, int out_size, void* d_ws, size_t ws_size,
                              hipStream_t stream) {
    const float* ftr    = (const float*)d_in[0];
    const float* tftr   = (const float*)d_in[1];
    const int*   label  = (const int*)d_in[2];
    const float* protos = (const float*)d_in[3];
    const int*   idH    = (const int*)d_in[4];
    float* out = (float*)d_out;
    int*   map = (int*)d_ws;   // NUM_IDS int32 = 400 KB of scratch

    (void)in_sizes; (void)n_in; (void)out_size; (void)ws_size;

    init_map_kernel<<<(NUM_IDS + 255) / 256, 256, 0, stream>>>(map, out);
    scatter_map_kernel<<<1, BATCH, 0, stream>>>(label, map);
    couple_loss_kernel<<<(BATCH * KNEG) / 4, 256, 0, stream>>>(
        ftr, tftr, label, protos, idH, map, out);
}

// Round 2
// 278.728 us; speedup vs baseline: 1.4868x; 1.4868x over previous
//
#include <hip/hip_runtime.h>

// CoupleLoss: protos = id_prototypes with rows[label] := teachor_ftr (last write
// wins on duplicate labels = numpy semantics), gi = protos[idH[label,:K]],
// loss = mean(relu(dot(gi, ftr - teachor_ftr) - MARGIN))
// (smrs - tmrs = dot(gi, ftr - teachor)).
//
// R2 structure: one block per b (512 blocks x 256 thr). Overwritten-id detection
// via a 100k-bit bitmap in LDS (no global map, no init/scatter kernels). Each
// wave gathers 25 prototype rows in batches of 5 for MLP.

#define NUM_IDS 100000
#define FEAT    512
#define BATCH   512
#define KNEG    100
#define MARGIN  0.03f
#define NBM     ((NUM_IDS + 31) / 32)   // 3125 u32 = 12.5 KB

__device__ __forceinline__ float dot8(float4 a, float4 c, float4 da, float4 db) {
    return a.x*da.x + a.y*da.y + a.z*da.z + a.w*da.w
         + c.x*db.x + c.y*db.y + c.z*db.z + c.w*db.w;
}

__global__ __launch_bounds__(256) void couple_main(
    const float* __restrict__ ftr,
    const float* __restrict__ tftr,
    const int*   __restrict__ label,
    const float* __restrict__ protos,
    const int*   __restrict__ idH,
    float*       __restrict__ bsums)
{
    __shared__ unsigned bm[NBM];
    __shared__ int   ls[BATCH];
    __shared__ int   rowsrc[KNEG];
    __shared__ float wsum[4];

    const int t    = threadIdx.x;
    const int lane = t & 63;
    const int wave = t >> 6;
    const int b    = blockIdx.x;

    // Stage labels into LDS; clear bitmap.
    ls[t]       = label[t];
    ls[t + 256] = label[t + 256];
    for (int i = t; i < NBM; i += 256) bm[i] = 0u;
    __syncthreads();
    {
        int l0 = ls[t], l1 = ls[t + 256];
        atomicOr(&bm[l0 >> 5], 1u << (l0 & 31));
        atomicOr(&bm[l1 >> 5], 1u << (l1 & 31));
    }
    const int myl = label[b];   // wave-uniform scalar load
    __syncthreads();

    // Resolve the 100 neg sources. Encoding: src >= 0 -> tftr row src (id was
    // overwritten; src = max batch idx with that label = numpy last-write-wins);
    // src < 0 -> protos row (~src).
    if (t < KNEG) {
        int nid = idH[myl * KNEG + t];
        int src = ~nid;
        if (bm[nid >> 5] & (1u << (nid & 31))) {     // rare (~0.5 per block)
            int m = -1;
            const int4* l4 = (const int4*)ls;
            #pragma unroll 4
            for (int j = 0; j < BATCH / 4; ++j) {
                int4 v = l4[j];
                if (v.x == nid) m = 4*j;
                if (v.y == nid) m = 4*j + 1;
                if (v.z == nid) m = 4*j + 2;
                if (v.w == nid) m = 4*j + 3;
            }
            src = m;
        }
        rowsrc[t] = src;
    }

    // Per-lane diff fragment: d = ftr_b - tftr_b, 8 floats/lane.
    const float4* f4 = (const float4*)(ftr  + (size_t)b * FEAT);
    const float4* t4 = (const float4*)(tftr + (size_t)b * FEAT);
    float4 fa = f4[lane], fb = f4[lane + 64];
    float4 ta = t4[lane], tb = t4[lane + 64];
    float4 da = {fa.x - ta.x, fa.y - ta.y, fa.z - ta.z, fa.w - ta.w};
    float4 db = {fb.x - tb.x, fb.y - tb.y, fb.z - tb.z, fb.w - tb.w};
    __syncthreads();

    // Each wave: 25 contiguous k's, processed 5 at a time (10 float4 loads in
    // flight per batch for MLP).
    float acc = 0.0f;
    const int kbase = wave * 25;
    #pragma unroll
    for (int jb = 0; jb < 5; ++jb) {
        const int kk = kbase + jb * 5;
        const float4* g[5];
        #pragma unroll
        for (int u = 0; u < 5; ++u) {
            int s = rowsrc[kk + u];
            g[u] = (s >= 0) ? (const float4*)(tftr   + (size_t)s    * FEAT)
                            : (const float4*)(protos + (size_t)(~s) * FEAT);
        }
        float4 a0 = g[0][lane], c0 = g[0][lane + 64];
        float4 a1 = g[1][lane], c1 = g[1][lane + 64];
        float4 a2 = g[2][lane], c2 = g[2][lane + 64];
        float4 a3 = g[3][lane], c3 = g[3][lane + 64];
        float4 a4 = g[4][lane], c4 = g[4][lane + 64];

        float s0 = dot8(a0, c0, da, db);
        float s1 = dot8(a1, c1, da, db);
        float s2 = dot8(a2, c2, da, db);
        float s3 = dot8(a3, c3, da, db);
        float s4 = dot8(a4, c4, da, db);

        #pragma unroll
        for (int off = 32; off >= 1; off >>= 1) {   // 5 interleaved butterflies
            s0 += __shfl_xor(s0, off, 64);
            s1 += __shfl_xor(s1, off, 64);
            s2 += __shfl_xor(s2, off, 64);
            s3 += __shfl_xor(s3, off, 64);
            s4 += __shfl_xor(s4, off, 64);
        }
        acc += fmaxf(s0 - MARGIN, 0.0f) + fmaxf(s1 - MARGIN, 0.0f)
             + fmaxf(s2 - MARGIN, 0.0f) + fmaxf(s3 - MARGIN, 0.0f)
             + fmaxf(s4 - MARGIN, 0.0f);
    }

    if (lane == 0) wsum[wave] = acc;
    __syncthreads();
    if (t == 0) bsums[b] = wsum[0] + wsum[1] + wsum[2] + wsum[3];
}

// Reduce 512 per-block sums -> mean. One block, 256 threads.
__global__ __launch_bounds__(256) void couple_finalize(
    const float* __restrict__ bsums, float* __restrict__ out)
{
    const int t = threadIdx.x;
    float v = bsums[t] + bsums[t + 256];
    #pragma unroll
    for (int off = 32; off >= 1; off >>= 1) v += __shfl_xor(v, off, 64);
    __shared__ float w[4];
    if ((t & 63) == 0) w[t >> 6] = v;
    __syncthreads();
    if (t == 0) out[0] = (w[0] + w[1] + w[2] + w[3]) * (1.0f / (BATCH * KNEG));
}

extern "C" void kernel_launch(void* const* d_in, const int* in_sizes, int n_in,
                              void* d_out, int out_size, void* d_ws, size_t ws_size,
                              hipStream_t stream) {
    const float* ftr    = (const float*)d_in[0];
    const float* tftr   = (const float*)d_in[1];
    const int*   label  = (const int*)d_in[2];
    const float* protos = (const float*)d_in[3];
    const int*   idH    = (const int*)d_in[4];
    float* out   = (float*)d_out;
    float* bsums = (float*)d_ws;   // 512 floats of scratch (no init needed)

    (void)in_sizes; (void)n_in; (void)out_size; (void)ws_size;

    couple_main<<<BATCH, 256, 0, stream>>>(ftr, tftr, label, protos, idH, bsums);
    couple_finalize<<<1, 256, 0, stream>>>(bsums, out);
}